// Round 7
// baseline (531.551 us; speedup 1.0000x reference)
//
#include <hip/hip_runtime.h>
#include <hip/hip_bf16.h>
#include <stdint.h>

// eidosNeighborMixer on MI355X:
//   pass 0a: W' = rotate(W, theta0+theta1) folded, transposed to Wt[N][K], bf16
//   pass 0b: b' = rotate(b); zero page
//   pass 0c: xbp = bf16(x) with zero rows at s'=0 and s'=8193 (padded seq)
//   pass 1 : GEMM  out = A @ Wt^T + b'   (A[m,k] = xbp[b][s + k/1024][k%1024])
//            256x256 tile, BK=32, 8 waves (2Mx4N).
//            A-operands load DIRECT global->VGPR (no LDS): kills the LDS-pipe
//            bottleneck (was 1408 cyc/kt vs MFMA 1242). B stays in a 4-deep
//            LDS ring (XOR-swizzled) staged via global_load_lds. Counted
//            waits: vmcnt(8)+lgkm(4) pre-cluster0, vmcnt(6) pre-cluster1,
//            one barrier/kt. A-addresses = uniform SGPR base + lane offset.
//   pass 2 : grouped (d%7) RMS norm, in-place on d_out

#define SEQ 8192
#define NB 4
#define DM 1024
#define KD 3072

typedef __attribute__((ext_vector_type(8))) short short8_t;
typedef __attribute__((ext_vector_type(4))) float f32x4;

__device__ __forceinline__ unsigned short f2bf(float f) {
  union { float f; uint32_t u; } v; v.f = f;
  return (unsigned short)((v.u + 0x7fffu + ((v.u >> 16) & 1u)) >> 16);  // RNE
}

__device__ __forceinline__ void async_ld16(const void* g, void* l) {
  __builtin_amdgcn_global_load_lds(
      (const __attribute__((address_space(1))) uint32_t*)g,
      (__attribute__((address_space(3))) uint32_t*)(uint32_t)(uintptr_t)l,
      16, 0, 0);
}

// ---------------- prep: rotate+transpose W -> Wt[N][K] bf16 ----------------
__global__ __launch_bounds__(256) void prep_w(const float* __restrict__ W,
                                              const float* __restrict__ theta,
                                              unsigned short* __restrict__ Wt) {
  __shared__ float csc[32], css[32];
  __shared__ unsigned short tile[64][72];  // [n_local][k_local], padded
  const int bk = blockIdx.x % 48, bn = blockIdx.x / 48;
  const int k0 = bk * 64, n0 = bn * 64;
  const int t = threadIdx.x;
  if (t < 32) {
    int d = n0 / 2 + t;
    float ang = theta[d] + theta[512 + d];
    csc[t] = cosf(ang); css[t] = sinf(ang);
  }
  __syncthreads();
#pragma unroll
  for (int i = 0; i < 8; ++i) {
    int idx = i * 256 + t;           // 2048 pairs = 64 k-rows x 32 pairs
    int pr = idx >> 5;               // k row 0..63
    int pc = idx & 31;               // pair col 0..31
    const float2 w2 = *(const float2*)&W[(size_t)(k0 + pr) * DM + n0 + pc * 2];
    float c = csc[pc], s = css[pc];
    tile[pc * 2][pr]     = f2bf(w2.x * c - w2.y * s);
    tile[pc * 2 + 1][pr] = f2bf(w2.x * s + w2.y * c);
  }
  __syncthreads();
#pragma unroll
  for (int i = 0; i < 16; ++i) {
    int idx = i * 256 + t;           // 4096 elems
    int r = idx >> 6, cdx = idx & 63;
    Wt[(size_t)(n0 + r) * KD + k0 + cdx] = tile[r][cdx];
  }
}

// ---------------- prep: rotated bias + zero page ----------------
__global__ void prep_bias(const float* __restrict__ b, const float* __restrict__ theta,
                          float* __restrict__ biasp, float* __restrict__ zp) {
  const int t = threadIdx.x;  // 512
  float ang = theta[t] + theta[512 + t];
  float c = cosf(ang), s = sinf(ang);
  float be = b[2 * t], bo = b[2 * t + 1];
  biasp[2 * t]     = be * c - bo * s;
  biasp[2 * t + 1] = be * s + bo * c;
  if (t < 256) ((float4*)zp)[t] = make_float4(0.f, 0.f, 0.f, 0.f);
}

// ---------------- prep: x -> bf16, seq-padded ----------------
__global__ __launch_bounds__(256) void prep_x(const float* __restrict__ x,
                                              unsigned short* __restrict__ xbp) {
  const size_t total = (size_t)NB * 8194 * 128;  // 16B chunks (8 bf16)
  for (size_t i = (size_t)blockIdx.x * 256 + threadIdx.x; i < total;
       i += (size_t)gridDim.x * 256) {
    int d8 = (int)(i & 127);
    size_t rem = i >> 7;
    int sp = (int)(rem % 8194);
    size_t bb = rem / 8194;
    uint4 o = make_uint4(0u, 0u, 0u, 0u);
    if (sp > 0 && sp < 8193) {
      const float4* src = (const float4*)(x + (bb * SEQ + (size_t)(sp - 1)) * DM + d8 * 8);
      float4 lo = src[0], hi = src[1];
      o.x = (uint32_t)f2bf(lo.x) | ((uint32_t)f2bf(lo.y) << 16);
      o.y = (uint32_t)f2bf(lo.z) | ((uint32_t)f2bf(lo.w) << 16);
      o.z = (uint32_t)f2bf(hi.x) | ((uint32_t)f2bf(hi.y) << 16);
      o.w = (uint32_t)f2bf(hi.z) | ((uint32_t)f2bf(hi.w) << 16);
    }
    ((uint4*)xbp)[i] = o;
  }
}

// ---- GEMM: 256x256, BK=32, A direct global->reg, B via LDS ring -----------
__global__ __launch_bounds__(512, 2) void gemm256(const unsigned short* __restrict__ xbp,
                                                  const unsigned short* __restrict__ Wt,
                                                  const float* __restrict__ biasp,
                                                  float* __restrict__ out) {
  __shared__ __align__(16) unsigned char Bs[4][16384];  // [buf][256 nrow][32 bf16]

  const int tid = threadIdx.x;
  const int lane = tid & 63;
  const int wid = tid >> 6;
  const int wm = wid >> 2, wn = wid & 3;      // 2M x 4N wave grid
  const int row16 = lane & 15, kgrp = lane >> 4;

  // XCD-bijective swizzle: 512 blocks = 8 XCD x (16 mtiles x 4 ntiles)
  const int L = blockIdx.x;
  const int xcd = L & 7;
  const int j = L >> 3;
  const int mtile = xcd * 16 + (j >> 2);
  const int ntile = j & 3;

  const int n0 = ntile * 256;
  const int batch = mtile >> 5;
  const int s0 = (mtile & 31) * 256;
  const size_t m0 = (size_t)mtile * 256;

  // A global lane offsets (element units), per fragment; kbase(kt) is uniform
  size_t arow[8];
#pragma unroll
  for (int mi = 0; mi < 4; ++mi) {
    arow[mi] = (size_t)(wm * 128 + mi * 16 + row16) * DM + kgrp * 8;
    arow[mi + 4] = arow[mi] + (size_t)64 * DM;
  }
  const size_t abase0 = ((size_t)batch * 8194 + (size_t)s0) * DM;

  // B fragment LDS byte offsets (thread-constant), XOR chunk swizzle
  int boff[4];
#pragma unroll
  for (int ni = 0; ni < 4; ++ni) {
    int r = wn * 64 + ni * 16 + row16;
    boff[ni] = r * 64 + (kgrp ^ ((r >> 1) & 3)) * 16;
  }

  // staging: LDS dest LINEAR; global source chunk pre-swizzled (same XOR)
  auto stageB = [&](int kt, int buf) {
    const int kb = kt * 32;
#pragma unroll
    for (int i = 0; i < 2; ++i) {
      int idx = i * 512 + tid;
      int row = idx >> 2, c16 = idx & 3;
      int cs = c16 ^ ((row >> 1) & 3);
      async_ld16(Wt + (size_t)(n0 + row) * KD + kb + cs * 8, &Bs[buf][idx * 16]);
    }
  };

  f32x4 acc[8][4];
#pragma unroll
  for (int a = 0; a < 8; ++a)
#pragma unroll
    for (int b = 0; b < 4; ++b) acc[a][b] = (f32x4){0.f, 0.f, 0.f, 0.f};

  short8_t af0A[4], af0B[4], bfA[4], bfB[4], af1r[4];

  // prologue: stage B kt 0,1,2; A frags for kt 0 (newest 4); confirm stages
  stageB(0, 0); stageB(1, 1); stageB(2, 2);
  {
    const size_t kb0 = abase0;  // kt=0: c=0, ksb=0
#pragma unroll
    for (int mi = 0; mi < 4; ++mi)
      af0A[mi] = *(const short8_t*)(xbp + kb0 + arow[mi]);
  }
  asm volatile("s_waitcnt vmcnt(4)" ::: "memory");  // all 3 B stages landed
  __builtin_amdgcn_s_barrier();
#pragma unroll
  for (int ni = 0; ni < 4; ++ni) bfA[ni] = *(const short8_t*)(&Bs[0][0] + boff[ni]);
  __builtin_amdgcn_sched_barrier(0);

  // Steady-state ledger (FIFO sets): carried at top = {stageB(kt+2):2, af0(kt):4}.
  // Issue af1(kt):4 [pinned first], stageB(kt+3):2, af0(kt+1):4, bfN(kt+1):4(lds).
  // vmcnt(8) drains all carried (af0C ready); lgkm(4) drains bfC.
  // vmcnt(6) drains af1. One barrier at bottom.
  auto body = [&](int kt, int buf, int doStage, int doNextA, int doNextB,
                  int vmTop, int vmMid, int lgTop,
                  short8_t (&af0C)[4], short8_t (&bfC)[4],
                  short8_t (&af0N)[4], short8_t (&bfN)[4]) {
    const int nbuf = (buf + 1) & 3, sbuf = (buf + 3) & 3;
    const int c = kt >> 5, ksb = (kt & 31) * 32;
    const size_t kbase = abase0 + (size_t)c * DM + ksb;
    // af1 (this kt, M-half1) pinned first so vmMid can count it
#pragma unroll
    for (int mi = 0; mi < 4; ++mi)
      af1r[mi] = *(const short8_t*)(xbp + kbase + arow[mi + 4]);
    __builtin_amdgcn_sched_barrier(0);
    if (doStage) stageB(kt + 3, sbuf);
    if (doNextA) {
      const int c2 = (kt + 1) >> 5, ksb2 = ((kt + 1) & 31) * 32;
      const size_t kbase2 = abase0 + (size_t)c2 * DM + ksb2;
#pragma unroll
      for (int mi = 0; mi < 4; ++mi)
        af0N[mi] = *(const short8_t*)(xbp + kbase2 + arow[mi]);
    }
    if (doNextB) {
#pragma unroll
      for (int ni = 0; ni < 4; ++ni)
        bfN[ni] = *(const short8_t*)(&Bs[nbuf][0] + boff[ni]);
    }
    if (vmTop == 8)      asm volatile("s_waitcnt vmcnt(8) lgkmcnt(4)" ::: "memory");
    else if (lgTop == 4) asm volatile("s_waitcnt vmcnt(4) lgkmcnt(4)" ::: "memory");
    else                 asm volatile("s_waitcnt vmcnt(4) lgkmcnt(0)" ::: "memory");
    __builtin_amdgcn_sched_barrier(0);
    __builtin_amdgcn_s_setprio(1);
#pragma unroll
    for (int mi = 0; mi < 4; ++mi)
#pragma unroll
      for (int ni = 0; ni < 4; ++ni)
        acc[mi][ni] = __builtin_amdgcn_mfma_f32_16x16x32_bf16(
            af0C[mi], bfC[ni], acc[mi][ni], 0, 0, 0);
    __builtin_amdgcn_s_setprio(0);
    if (vmMid == 6)      asm volatile("s_waitcnt vmcnt(6)" ::: "memory");
    else if (vmMid == 4) asm volatile("s_waitcnt vmcnt(4)" ::: "memory");
    else                 asm volatile("s_waitcnt vmcnt(0)" ::: "memory");
    __builtin_amdgcn_sched_barrier(0);
    __builtin_amdgcn_s_setprio(1);
#pragma unroll
    for (int mi = 0; mi < 4; ++mi)
#pragma unroll
      for (int ni = 0; ni < 4; ++ni)
        acc[mi + 4][ni] = __builtin_amdgcn_mfma_f32_16x16x32_bf16(
            af1r[mi], bfC[ni], acc[mi + 4][ni], 0, 0, 0);
    __builtin_amdgcn_s_setprio(0);
    __builtin_amdgcn_sched_barrier(0);
    __builtin_amdgcn_s_barrier();
  };

  for (int kt4 = 0; kt4 < 92; kt4 += 4) {
    body(kt4 + 0, 0, 1, 1, 1, 8, 6, 4, af0A, bfA, af0B, bfB);
    body(kt4 + 1, 1, 1, 1, 1, 8, 6, 4, af0B, bfB, af0A, bfA);
    body(kt4 + 2, 2, 1, 1, 1, 8, 6, 4, af0A, bfA, af0B, bfB);
    body(kt4 + 3, 3, 1, 1, 1, 8, 6, 4, af0B, bfB, af0A, bfA);
  }
  // tail: kt93-95 stop staging; counted drains per the FIFO ledger
  body(92, 0, 1, 1, 1, 8, 6, 4, af0A, bfA, af0B, bfB);
  body(93, 1, 0, 1, 1, 8, 4, 4, af0B, bfB, af0A, bfA);
  body(94, 2, 0, 1, 1, 8, 4, 4, af0A, bfA, af0B, bfB);
  body(95, 3, 0, 0, 0, 4, 0, 0, af0B, bfB, af0A, bfA);

  // epilogue: C[row=kgrp*4+r, col=row16] per 16x16 fragment
#pragma unroll
  for (int mi = 0; mi < 8; ++mi) {
    size_t grow = m0 + (size_t)(wm * 128 + mi * 16 + kgrp * 4);
#pragma unroll
    for (int ni = 0; ni < 4; ++ni) {
      int col = n0 + wn * 64 + ni * 16 + row16;
      float bia = biasp[col];
      float* op = out + grow * DM + col;
#pragma unroll
      for (int r = 0; r < 4; ++r) op[(size_t)r * DM] = acc[mi][ni][r] + bia;
    }
  }
}

// ---------------- fallback GEMM (fp32 A direct), 128x128 2-barrier ----------
__global__ __launch_bounds__(256) void gemm_fb(const float* __restrict__ Ag,
                                               const unsigned short* __restrict__ Wt,
                                               const float* __restrict__ biasp,
                                               const float* __restrict__ zp,
                                               float* __restrict__ out) {
  __shared__ __align__(16) unsigned char As[128 * 64 * 4];
  __shared__ __align__(16) unsigned char Bs[128 * 64 * 2];

  const int tid = threadIdx.x;
  const int lane = tid & 63;
  const int wid = tid >> 6;
  const int wm = wid >> 1, wn = wid & 1;
  const int row16 = lane & 15, kgrp = lane >> 4;

  const int L = blockIdx.x;
  const int xcd = L & 7;
  const int j = L >> 3;
  const int mtile = xcd * 32 + (j >> 3);
  const int ntile = j & 7;

  const int n0 = ntile * 128;
  const int batch = mtile >> 6;
  const int s0 = (mtile & 63) * 128;
  const size_t m0 = (size_t)mtile * 128;

  f32x4 acc[4][4];
#pragma unroll
  for (int a = 0; a < 4; ++a)
#pragma unroll
    for (int b = 0; b < 4; ++b) acc[a][b] = (f32x4){0.f, 0.f, 0.f, 0.f};

  for (int kt = 0; kt < 48; ++kt) {
    const int c = kt >> 4;
    const int ksb = (kt & 15) * 64;
    __syncthreads();
#pragma unroll
    for (int it = 0; it < 8; ++it) {
      int f16 = it * 256 + tid;
      int row = f16 >> 4, c16 = f16 & 15;
      int c16s = c16 ^ (row & 7);
      int s = s0 + row + c - 1;
      const float* src = (s >= 0 && s < SEQ)
          ? Ag + ((size_t)batch * SEQ + (size_t)s) * DM + ksb + c16s * 4
          : zp + c16s * 4;
      async_ld16(src, As + f16 * 16);
    }
#pragma unroll
    for (int it = 0; it < 4; ++it) {
      int f16 = it * 256 + tid;
      int row = f16 >> 3, c16 = f16 & 7;
      int c16s = c16 ^ (row & 7);
      const unsigned short* src = Wt + (size_t)(n0 + row) * KD + kt * 64 + c16s * 8;
      async_ld16(src, Bs + f16 * 16);
    }
    __syncthreads();

#pragma unroll
    for (int kk = 0; kk < 2; ++kk) {
      short8_t af[4], bfr[4];
#pragma unroll
      for (int mi = 0; mi < 4; ++mi) {
        int r = wm * 64 + mi * 16 + row16;
        int kb = kk * 128 + kgrp * 32;
        f32x4 lo = *(const f32x4*)(As + r * 256 + (kb ^ ((r & 7) << 4)));
        f32x4 hi = *(const f32x4*)(As + r * 256 + ((kb + 16) ^ ((r & 7) << 4)));
        union { short8_t v; unsigned short u[8]; } pk;
        pk.u[0] = f2bf(lo[0]); pk.u[1] = f2bf(lo[1]);
        pk.u[2] = f2bf(lo[2]); pk.u[3] = f2bf(lo[3]);
        pk.u[4] = f2bf(hi[0]); pk.u[5] = f2bf(hi[1]);
        pk.u[6] = f2bf(hi[2]); pk.u[7] = f2bf(hi[3]);
        af[mi] = pk.v;
      }
#pragma unroll
      for (int ni = 0; ni < 4; ++ni) {
        int r = wn * 64 + ni * 16 + row16;
        int kb = kk * 64 + kgrp * 16;
        bfr[ni] = *(const short8_t*)(Bs + r * 128 + (kb ^ ((r & 7) << 4)));
      }
#pragma unroll
      for (int mi = 0; mi < 4; ++mi)
#pragma unroll
        for (int ni = 0; ni < 4; ++ni)
          acc[mi][ni] = __builtin_amdgcn_mfma_f32_16x16x32_bf16(
              af[mi], bfr[ni], acc[mi][ni], 0, 0, 0);
    }
  }

#pragma unroll
  for (int mi = 0; mi < 4; ++mi) {
    size_t grow = m0 + (size_t)(wm * 64 + mi * 16 + kgrp * 4);
#pragma unroll
    for (int ni = 0; ni < 4; ++ni) {
      int col = n0 + wn * 64 + ni * 16 + row16;
      float bia = biasp[col];
      float* op = out + grow * DM + col;
#pragma unroll
      for (int r = 0; r < 4; ++r) op[(size_t)r * DM] = acc[mi][ni][r] + bia;
    }
  }
}

// ---------------- pass 2: grouped (d%7) RMS norm, in-place ----------------
__global__ __launch_bounds__(256) void norm_kernel(float* __restrict__ y,
                                                   const float* __restrict__ gamma) {
  const int tid = threadIdx.x, lane = tid & 63, wv = tid >> 6;
  const size_t row = (size_t)blockIdx.x * 4 + wv;   // one wave per row
  float4* rp = (float4*)(y + row * DM);
  const float4* gp = (const float4*)gamma;
  float4 v[4];
#pragma unroll
  for (int jj = 0; jj < 4; ++jj) v[jj] = rp[jj * 64 + lane];

  float ss[7] = {0.f, 0.f, 0.f, 0.f, 0.f, 0.f, 0.f};
#pragma unroll
  for (int jj = 0; jj < 4; ++jj) {
    const float vv[4] = {v[jj].x, v[jj].y, v[jj].z, v[jj].w};
#pragma unroll
    for (int i = 0; i < 4; ++i) {
      int d = (jj * 64 + lane) * 4 + i;
      int g = d % 7;
      float sq = vv[i] * vv[i];
#pragma unroll
      for (int t = 0; t < 7; ++t) ss[t] += (g == t) ? sq : 0.f;
    }
  }
#pragma unroll
  for (int t = 0; t < 7; ++t) {
#pragma unroll
    for (int off = 32; off >= 1; off >>= 1) ss[t] += __shfl_xor(ss[t], off, 64);
  }
  float inv[7];
#pragma unroll
  for (int t = 0; t < 7; ++t) {
    float cnt = (t < 2) ? 147.f : 146.f;   // D=1024: groups 0,1 have 147 dims
    inv[t] = rsqrtf(ss[t] / cnt + 1e-6f);
  }
#pragma unroll
  for (int jj = 0; jj < 4; ++jj) {
    float4 g4 = gp[jj * 64 + lane];
    const float vv[4] = {v[jj].x, v[jj].y, v[jj].z, v[jj].w};
    const float gg[4] = {g4.x, g4.y, g4.z, g4.w};
    float o[4];
#pragma unroll
    for (int i = 0; i < 4; ++i) {
      int d = (jj * 64 + lane) * 4 + i;
      int g = d % 7;
      float iv = inv[0];
#pragma unroll
      for (int t = 1; t < 7; ++t) iv = (g == t) ? inv[t] : iv;
      o[i] = vv[i] * iv * gg[i];
    }
    rp[jj * 64 + lane] = make_float4(o[0], o[1], o[2], o[3]);
  }
}

extern "C" void kernel_launch(void* const* d_in, const int* in_sizes, int n_in,
                              void* d_out, int out_size, void* d_ws, size_t ws_size,
                              hipStream_t stream) {
  const float* x     = (const float*)d_in[0];
  const float* W     = (const float*)d_in[1];
  const float* b     = (const float*)d_in[2];
  const float* theta = (const float*)d_in[3];
  const float* gamma = (const float*)d_in[4];
  float* out = (float*)d_out;
  (void)in_sizes; (void)n_in; (void)out_size;

  char* ws = (char*)d_ws;
  unsigned short* Wt = (unsigned short*)ws;                 // 6,291,456 B
  float* biasp = (float*)(ws + 6291456);                    // 4 KiB
  float* zp    = (float*)(ws + 6291456 + 4096);             // 4 KiB zeros
  unsigned short* xbp = (unsigned short*)(ws + 6299648);    // 67,158,016 B
  const size_t needA = 6299648 + (size_t)NB * 8194 * DM * 2;

  prep_w<<<dim3(768), dim3(256), 0, stream>>>(W, theta, Wt);
  prep_bias<<<dim3(1), dim3(512), 0, stream>>>(b, theta, biasp, zp);

  if (ws_size >= needA) {
    prep_x<<<dim3(4096), dim3(256), 0, stream>>>(x, xbp);
    gemm256<<<dim3(512), dim3(512), 0, stream>>>(xbp, Wt, biasp, out);
  } else {
    gemm_fb<<<dim3(2048), dim3(256), 0, stream>>>(x, Wt, biasp, zp, out);
  }
  norm_kernel<<<dim3(8192), dim3(256), 0, stream>>>(out, gamma);
}

// Round 8
// 274.630 us; speedup vs baseline: 1.9355x; 1.9355x over previous
//
#include <hip/hip_runtime.h>
#include <hip/hip_bf16.h>
#include <stdint.h>

// eidosNeighborMixer on MI355X:
//   pass 0a: W' = rotate(W, theta0+theta1) folded, transposed to Wt[N][K], bf16
//   pass 0b: b' = rotate(b); zero page
//   pass 0c: xbp = bf16(x) with zero rows at s'=0 and s'=8193 (padded seq)
//   pass 1 : GEMM  out = A @ Wt^T + b'   (A[m,k] = xbp[b][s + k/1024][k%1024])
//            256x256 tile, BK=32, 8 waves (2Mx4N), 4-deep LDS ring (A+B),
//            16x16x32 MFMA. FULL cross-iteration register prefetch: all 12
//            fragments (8 A + 4 B) for kt+1 are ds_read during kt; the only
//            lgkm wait is top-of-tile lgkm(12) on reads issued a full K-tile
//            ago (free). 32 MFMA run back-to-back with no mid-cluster wait.
//            vmcnt(4) at bottom keeps the 2-K-tile staging lead. XOR chunk
//            swizzle (both-sides) keeps LDS conflicts at 0.
//   pass 2 : grouped (d%7) RMS norm, in-place on d_out

#define SEQ 8192
#define NB 4
#define DM 1024
#define KD 3072

typedef __attribute__((ext_vector_type(8))) short short8_t;
typedef __attribute__((ext_vector_type(4))) float f32x4;

__device__ __forceinline__ unsigned short f2bf(float f) {
  union { float f; uint32_t u; } v; v.f = f;
  return (unsigned short)((v.u + 0x7fffu + ((v.u >> 16) & 1u)) >> 16);  // RNE
}

__device__ __forceinline__ void async_ld16(const void* g, void* l) {
  __builtin_amdgcn_global_load_lds(
      (const __attribute__((address_space(1))) uint32_t*)g,
      (__attribute__((address_space(3))) uint32_t*)(uint32_t)(uintptr_t)l,
      16, 0, 0);
}

// ---------------- prep: rotate+transpose W -> Wt[N][K] bf16 ----------------
__global__ __launch_bounds__(256) void prep_w(const float* __restrict__ W,
                                              const float* __restrict__ theta,
                                              unsigned short* __restrict__ Wt) {
  __shared__ float csc[32], css[32];
  __shared__ unsigned short tile[64][72];  // [n_local][k_local], padded
  const int bk = blockIdx.x % 48, bn = blockIdx.x / 48;
  const int k0 = bk * 64, n0 = bn * 64;
  const int t = threadIdx.x;
  if (t < 32) {
    int d = n0 / 2 + t;
    float ang = theta[d] + theta[512 + d];
    csc[t] = cosf(ang); css[t] = sinf(ang);
  }
  __syncthreads();
#pragma unroll
  for (int i = 0; i < 8; ++i) {
    int idx = i * 256 + t;           // 2048 pairs = 64 k-rows x 32 pairs
    int pr = idx >> 5;               // k row 0..63
    int pc = idx & 31;               // pair col 0..31
    const float2 w2 = *(const float2*)&W[(size_t)(k0 + pr) * DM + n0 + pc * 2];
    float c = csc[pc], s = css[pc];
    tile[pc * 2][pr]     = f2bf(w2.x * c - w2.y * s);
    tile[pc * 2 + 1][pr] = f2bf(w2.x * s + w2.y * c);
  }
  __syncthreads();
#pragma unroll
  for (int i = 0; i < 16; ++i) {
    int idx = i * 256 + t;           // 4096 elems
    int r = idx >> 6, cdx = idx & 63;
    Wt[(size_t)(n0 + r) * KD + k0 + cdx] = tile[r][cdx];
  }
}

// ---------------- prep: rotated bias + zero page ----------------
__global__ void prep_bias(const float* __restrict__ b, const float* __restrict__ theta,
                          float* __restrict__ biasp, float* __restrict__ zp) {
  const int t = threadIdx.x;  // 512
  float ang = theta[t] + theta[512 + t];
  float c = cosf(ang), s = sinf(ang);
  float be = b[2 * t], bo = b[2 * t + 1];
  biasp[2 * t]     = be * c - bo * s;
  biasp[2 * t + 1] = be * s + bo * c;
  if (t < 256) ((float4*)zp)[t] = make_float4(0.f, 0.f, 0.f, 0.f);
}

// ---------------- prep: x -> bf16, seq-padded ----------------
__global__ __launch_bounds__(256) void prep_x(const float* __restrict__ x,
                                              unsigned short* __restrict__ xbp) {
  const size_t total = (size_t)NB * 8194 * 128;  // 16B chunks (8 bf16)
  for (size_t i = (size_t)blockIdx.x * 256 + threadIdx.x; i < total;
       i += (size_t)gridDim.x * 256) {
    int d8 = (int)(i & 127);
    size_t rem = i >> 7;
    int sp = (int)(rem % 8194);
    size_t bb = rem / 8194;
    uint4 o = make_uint4(0u, 0u, 0u, 0u);
    if (sp > 0 && sp < 8193) {
      const float4* src = (const float4*)(x + (bb * SEQ + (size_t)(sp - 1)) * DM + d8 * 8);
      float4 lo = src[0], hi = src[1];
      o.x = (uint32_t)f2bf(lo.x) | ((uint32_t)f2bf(lo.y) << 16);
      o.y = (uint32_t)f2bf(lo.z) | ((uint32_t)f2bf(lo.w) << 16);
      o.z = (uint32_t)f2bf(hi.x) | ((uint32_t)f2bf(hi.y) << 16);
      o.w = (uint32_t)f2bf(hi.z) | ((uint32_t)f2bf(hi.w) << 16);
    }
    ((uint4*)xbp)[i] = o;
  }
}

// ---- GEMM: 256x256, BK=32, 4-ring, full 12-fragment cross-iter prefetch ---
__global__ __launch_bounds__(512, 2) void gemm256(const unsigned short* __restrict__ xbp,
                                                  const unsigned short* __restrict__ Wt,
                                                  const float* __restrict__ biasp,
                                                  float* __restrict__ out) {
  __shared__ __align__(16) unsigned char As[4][16384];  // [buf][256 rows][32 bf16]
  __shared__ __align__(16) unsigned char Bs[4][16384];  // [buf][256 nrow][32 bf16]

  const int tid = threadIdx.x;
  const int lane = tid & 63;
  const int wid = tid >> 6;
  const int wm = wid >> 2, wn = wid & 3;      // 2M x 4N wave grid
  const int row16 = lane & 15, kgrp = lane >> 4;

  // XCD-bijective swizzle: 512 blocks = 8 XCD x (16 mtiles x 4 ntiles)
  const int L = blockIdx.x;
  const int xcd = L & 7;
  const int j = L >> 3;
  const int mtile = xcd * 16 + (j >> 2);
  const int ntile = j & 3;

  const int n0 = ntile * 256;
  const int batch = mtile >> 5;
  const int s0 = (mtile & 31) * 256;
  const size_t m0 = (size_t)mtile * 256;

  // fragment LDS byte offsets within a 16 KiB buffer (thread-constant)
  int aoff[8], boff[4];
#pragma unroll
  for (int mi = 0; mi < 4; ++mi) {
    int r = wm * 128 + mi * 16 + row16;
    aoff[mi] = r * 64 + (kgrp ^ ((r >> 1) & 3)) * 16;
    int r2 = r + 64;
    aoff[mi + 4] = r2 * 64 + (kgrp ^ ((r2 >> 1) & 3)) * 16;
  }
#pragma unroll
  for (int ni = 0; ni < 4; ++ni) {
    int r = wn * 64 + ni * 16 + row16;
    boff[ni] = r * 64 + (kgrp ^ ((r >> 1) & 3)) * 16;
  }

  // staging: LDS dest LINEAR; global source chunk pre-swizzled (same XOR)
  auto stageA = [&](int kt, int buf) {
    const int c = kt >> 5;
    const int ksb = (kt & 31) * 32;
    const size_t base = ((size_t)batch * 8194 + (size_t)(s0 + c)) * DM + ksb;
#pragma unroll
    for (int i = 0; i < 2; ++i) {
      int idx = i * 512 + tid;
      int row = idx >> 2, c16 = idx & 3;
      int cs = c16 ^ ((row >> 1) & 3);
      async_ld16(xbp + base + (size_t)row * DM + cs * 8, &As[buf][idx * 16]);
    }
  };
  auto stageB = [&](int kt, int buf) {
    const int kb = kt * 32;
#pragma unroll
    for (int i = 0; i < 2; ++i) {
      int idx = i * 512 + tid;
      int row = idx >> 2, c16 = idx & 3;
      int cs = c16 ^ ((row >> 1) & 3);
      async_ld16(Wt + (size_t)(n0 + row) * KD + kb + cs * 8, &Bs[buf][idx * 16]);
    }
  };

  f32x4 acc[8][4];
#pragma unroll
  for (int a = 0; a < 8; ++a)
#pragma unroll
    for (int b = 0; b < 4; ++b) acc[a][b] = (f32x4){0.f, 0.f, 0.f, 0.f};

  short8_t afA[8], bfA[4], afB[8], bfB[4];

  // prologue: stage kt 0,1,2; confirm 0 AND 1; read all 12 frags of kt 0
  stageA(0, 0); stageB(0, 0);
  stageA(1, 1); stageB(1, 1);
  stageA(2, 2); stageB(2, 2);
  asm volatile("s_waitcnt vmcnt(4)" ::: "memory");  // stage(0),(1) complete
  __builtin_amdgcn_s_barrier();
#pragma unroll
  for (int mi = 0; mi < 8; ++mi) afA[mi] = *(const short8_t*)(&As[0][0] + aoff[mi]);
#pragma unroll
  for (int ni = 0; ni < 4; ++ni) bfA[ni] = *(const short8_t*)(&Bs[0][0] + boff[ni]);
  __builtin_amdgcn_sched_barrier(0);

  // one K-tile. afC/bfC: all 12 frags for THIS kt, ds_read issued during kt-1
  // (drained by top lgkm(12) — free). afN/bfN: kt+1 prefetch, issued here,
  // drains under the 32-MFMA block + barrier + next top.
  auto body = [&](int kt, int buf, int doStage, int doNext, int vm4,
                  short8_t (&afC)[8], short8_t (&bfC)[4],
                  short8_t (&afN)[8], short8_t (&bfN)[4]) {
    const int nbuf = (buf + 1) & 3, sbuf = (buf + 3) & 3;
    if (doStage) { stageA(kt + 3, sbuf); stageB(kt + 3, sbuf); }
    if (doNext) {
#pragma unroll
      for (int mi = 0; mi < 8; ++mi)
        afN[mi] = *(const short8_t*)(&As[nbuf][0] + aoff[mi]);
#pragma unroll
      for (int ni = 0; ni < 4; ++ni)
        bfN[ni] = *(const short8_t*)(&Bs[nbuf][0] + boff[ni]);
      asm volatile("s_waitcnt lgkmcnt(12)" ::: "memory");
    } else {
      asm volatile("s_waitcnt lgkmcnt(0)" ::: "memory");
    }
    __builtin_amdgcn_sched_barrier(0);
    __builtin_amdgcn_s_setprio(1);
#pragma unroll
    for (int mi = 0; mi < 8; ++mi)
#pragma unroll
      for (int ni = 0; ni < 4; ++ni)
        acc[mi][ni] = __builtin_amdgcn_mfma_f32_16x16x32_bf16(
            afC[mi], bfC[ni], acc[mi][ni], 0, 0, 0);
    __builtin_amdgcn_s_setprio(0);
    if (vm4) asm volatile("s_waitcnt vmcnt(4)" ::: "memory");
    else     asm volatile("s_waitcnt vmcnt(0)" ::: "memory");
    __builtin_amdgcn_sched_barrier(0);
    __builtin_amdgcn_s_barrier();
  };

  for (int kt4 = 0; kt4 < 92; kt4 += 4) {
    body(kt4 + 0, 0, 1, 1, 1, afA, bfA, afB, bfB);
    body(kt4 + 1, 1, 1, 1, 1, afB, bfB, afA, bfA);
    body(kt4 + 2, 2, 1, 1, 1, afA, bfA, afB, bfB);
    body(kt4 + 3, 3, 1, 1, 1, afB, bfB, afA, bfA);
  }
  // tail: kt92 stages kt95; kt93/94 drain staging; kt95 no prefetch
  body(92, 0, 1, 1, 1, afA, bfA, afB, bfB);
  body(93, 1, 0, 1, 0, afB, bfB, afA, bfA);
  body(94, 2, 0, 1, 0, afA, bfA, afB, bfB);
  body(95, 3, 0, 0, 0, afB, bfB, afA, bfA);

  // epilogue: C[row=kgrp*4+r, col=row16] per 16x16 fragment
#pragma unroll
  for (int mi = 0; mi < 8; ++mi) {
    size_t grow = m0 + (size_t)(wm * 128 + mi * 16 + kgrp * 4);
#pragma unroll
    for (int ni = 0; ni < 4; ++ni) {
      int col = n0 + wn * 64 + ni * 16 + row16;
      float bia = biasp[col];
      float* op = out + grow * DM + col;
#pragma unroll
      for (int r = 0; r < 4; ++r) op[(size_t)r * DM] = acc[mi][ni][r] + bia;
    }
  }
}

// ---------------- fallback GEMM (fp32 A direct), 128x128 2-barrier ----------
__global__ __launch_bounds__(256) void gemm_fb(const float* __restrict__ Ag,
                                               const unsigned short* __restrict__ Wt,
                                               const float* __restrict__ biasp,
                                               const float* __restrict__ zp,
                                               float* __restrict__ out) {
  __shared__ __align__(16) unsigned char As[128 * 64 * 4];
  __shared__ __align__(16) unsigned char Bs[128 * 64 * 2];

  const int tid = threadIdx.x;
  const int lane = tid & 63;
  const int wid = tid >> 6;
  const int wm = wid >> 1, wn = wid & 1;
  const int row16 = lane & 15, kgrp = lane >> 4;

  const int L = blockIdx.x;
  const int xcd = L & 7;
  const int j = L >> 3;
  const int mtile = xcd * 32 + (j >> 3);
  const int ntile = j & 7;

  const int n0 = ntile * 128;
  const int batch = mtile >> 6;
  const int s0 = (mtile & 63) * 128;
  const size_t m0 = (size_t)mtile * 128;

  f32x4 acc[4][4];
#pragma unroll
  for (int a = 0; a < 4; ++a)
#pragma unroll
    for (int b = 0; b < 4; ++b) acc[a][b] = (f32x4){0.f, 0.f, 0.f, 0.f};

  for (int kt = 0; kt < 48; ++kt) {
    const int c = kt >> 4;
    const int ksb = (kt & 15) * 64;
    __syncthreads();
#pragma unroll
    for (int it = 0; it < 8; ++it) {
      int f16 = it * 256 + tid;
      int row = f16 >> 4, c16 = f16 & 15;
      int c16s = c16 ^ (row & 7);
      int s = s0 + row + c - 1;
      const float* src = (s >= 0 && s < SEQ)
          ? Ag + ((size_t)batch * SEQ + (size_t)s) * DM + ksb + c16s * 4
          : zp + c16s * 4;
      async_ld16(src, As + f16 * 16);
    }
#pragma unroll
    for (int it = 0; it < 4; ++it) {
      int f16 = it * 256 + tid;
      int row = f16 >> 3, c16 = f16 & 7;
      int c16s = c16 ^ (row & 7);
      const unsigned short* src = Wt + (size_t)(n0 + row) * KD + kt * 64 + c16s * 8;
      async_ld16(src, Bs + f16 * 16);
    }
    __syncthreads();

#pragma unroll
    for (int kk = 0; kk < 2; ++kk) {
      short8_t af[4], bfr[4];
#pragma unroll
      for (int mi = 0; mi < 4; ++mi) {
        int r = wm * 64 + mi * 16 + row16;
        int kb = kk * 128 + kgrp * 32;
        f32x4 lo = *(const f32x4*)(As + r * 256 + (kb ^ ((r & 7) << 4)));
        f32x4 hi = *(const f32x4*)(As + r * 256 + ((kb + 16) ^ ((r & 7) << 4)));
        union { short8_t v; unsigned short u[8]; } pk;
        pk.u[0] = f2bf(lo[0]); pk.u[1] = f2bf(lo[1]);
        pk.u[2] = f2bf(lo[2]); pk.u[3] = f2bf(lo[3]);
        pk.u[4] = f2bf(hi[0]); pk.u[5] = f2bf(hi[1]);
        pk.u[6] = f2bf(hi[2]); pk.u[7] = f2bf(hi[3]);
        af[mi] = pk.v;
      }
#pragma unroll
      for (int ni = 0; ni < 4; ++ni) {
        int r = wn * 64 + ni * 16 + row16;
        int kb = kk * 64 + kgrp * 16;
        bfr[ni] = *(const short8_t*)(Bs + r * 128 + (kb ^ ((r & 7) << 4)));
      }
#pragma unroll
      for (int mi = 0; mi < 4; ++mi)
#pragma unroll
        for (int ni = 0; ni < 4; ++ni)
          acc[mi][ni] = __builtin_amdgcn_mfma_f32_16x16x32_bf16(
              af[mi], bfr[ni], acc[mi][ni], 0, 0, 0);
    }
  }

#pragma unroll
  for (int mi = 0; mi < 4; ++mi) {
    size_t grow = m0 + (size_t)(wm * 64 + mi * 16 + kgrp * 4);
#pragma unroll
    for (int ni = 0; ni < 4; ++ni) {
      int col = n0 + wn * 64 + ni * 16 + row16;
      float bia = biasp[col];
      float* op = out + grow * DM + col;
#pragma unroll
      for (int r = 0; r < 4; ++r) op[(size_t)r * DM] = acc[mi][ni][r] + bia;
    }
  }
}

// ---------------- pass 2: grouped (d%7) RMS norm, in-place ----------------
__global__ __launch_bounds__(256) void norm_kernel(float* __restrict__ y,
                                                   const float* __restrict__ gamma) {
  const int tid = threadIdx.x, lane = tid & 63, wv = tid >> 6;
  const size_t row = (size_t)blockIdx.x * 4 + wv;   // one wave per row
  float4* rp = (float4*)(y + row * DM);
  const float4* gp = (const float4*)gamma;
  float4 v[4];
#pragma unroll
  for (int jj = 0; jj < 4; ++jj) v[jj] = rp[jj * 64 + lane];

  float ss[7] = {0.f, 0.f, 0.f, 0.f, 0.f, 0.f, 0.f};
#pragma unroll
  for (int jj = 0; jj < 4; ++jj) {
    const float vv[4] = {v[jj].x, v[jj].y, v[jj].z, v[jj].w};
#pragma unroll
    for (int i = 0; i < 4; ++i) {
      int d = (jj * 64 + lane) * 4 + i;
      int g = d % 7;
      float sq = vv[i] * vv[i];
#pragma unroll
      for (int t = 0; t < 7; ++t) ss[t] += (g == t) ? sq : 0.f;
    }
  }
#pragma unroll
  for (int t = 0; t < 7; ++t) {
#pragma unroll
    for (int off = 32; off >= 1; off >>= 1) ss[t] += __shfl_xor(ss[t], off, 64);
  }
  float inv[7];
#pragma unroll
  for (int t = 0; t < 7; ++t) {
    float cnt = (t < 2) ? 147.f : 146.f;   // D=1024: groups 0,1 have 147 dims
    inv[t] = rsqrtf(ss[t] / cnt + 1e-6f);
  }
#pragma unroll
  for (int jj = 0; jj < 4; ++jj) {
    float4 g4 = gp[jj * 64 + lane];
    const float vv[4] = {v[jj].x, v[jj].y, v[jj].z, v[jj].w};
    const float gg[4] = {g4.x, g4.y, g4.z, g4.w};
    float o[4];
#pragma unroll
    for (int i = 0; i < 4; ++i) {
      int d = (jj * 64 + lane) * 4 + i;
      int g = d % 7;
      float iv = inv[0];
#pragma unroll
      for (int t = 1; t < 7; ++t) iv = (g == t) ? inv[t] : iv;
      o[i] = vv[i] * iv * gg[i];
    }
    rp[jj * 64 + lane] = make_float4(o[0], o[1], o[2], o[3]);
  }
}

extern "C" void kernel_launch(void* const* d_in, const int* in_sizes, int n_in,
                              void* d_out, int out_size, void* d_ws, size_t ws_size,
                              hipStream_t stream) {
  const float* x     = (const float*)d_in[0];
  const float* W     = (const float*)d_in[1];
  const float* b     = (const float*)d_in[2];
  const float* theta = (const float*)d_in[3];
  const float* gamma = (const float*)d_in[4];
  float* out = (float*)d_out;
  (void)in_sizes; (void)n_in; (void)out_size;

  char* ws = (char*)d_ws;
  unsigned short* Wt = (unsigned short*)ws;                 // 6,291,456 B
  float* biasp = (float*)(ws + 6291456);                    // 4 KiB
  float* zp    = (float*)(ws + 6291456 + 4096);             // 4 KiB zeros
  unsigned short* xbp = (unsigned short*)(ws + 6299648);    // 67,158,016 B
  const size_t needA = 6299648 + (size_t)NB * 8194 * DM * 2;

  prep_w<<<dim3(768), dim3(256), 0, stream>>>(W, theta, Wt);
  prep_bias<<<dim3(1), dim3(512), 0, stream>>>(b, theta, biasp, zp);

  if (ws_size >= needA) {
    prep_x<<<dim3(4096), dim3(256), 0, stream>>>(x, xbp);
    gemm256<<<dim3(512), dim3(512), 0, stream>>>(xbp, Wt, biasp, out);
  } else {
    gemm_fb<<<dim3(2048), dim3(256), 0, stream>>>(x, Wt, biasp, zp, out);
  }
  norm_kernel<<<dim3(8192), dim3(256), 0, stream>>>(out, gamma);
}

// Round 9
// 257.319 us; speedup vs baseline: 2.0657x; 1.0673x over previous
//
#include <hip/hip_runtime.h>
#include <hip/hip_bf16.h>
#include <stdint.h>

// eidosNeighborMixer on MI355X:
//   pass 0a: W' = rotate(W, theta0+theta1) folded, transposed to Wt[N][K], bf16
//   pass 0b: b' = rotate(b); zero page
//   pass 0c: xbp = bf16(x) with zero rows at s'=0 and s'=8193 (padded seq)
//   pass 1 : GEMM  out = A @ Wt^T + b'   (A[m,k] = xbp[b][s + k/1024][k%1024])
//            256x256 tile, BK=32, 16 waves (4Mx4N, 1024 thr), wave out 64x64
//            -> acc 64 regs -> ~120 total -> 4 waves/SIMD occupancy (TLP
//            hides LDS drains; the 2-waves/SIMD cap was R2-R8's real wall).
//            4-deep LDS ring, global_load_lds staging, XOR chunk swizzle,
//            counted vmcnt(4), lgkm(0)+setprio around the 16-MFMA cluster.
//   pass 2 : grouped (d%7) RMS norm, in-place on d_out

#define SEQ 8192
#define NB 4
#define DM 1024
#define KD 3072

typedef __attribute__((ext_vector_type(8))) short short8_t;
typedef __attribute__((ext_vector_type(4))) float f32x4;

__device__ __forceinline__ unsigned short f2bf(float f) {
  union { float f; uint32_t u; } v; v.f = f;
  return (unsigned short)((v.u + 0x7fffu + ((v.u >> 16) & 1u)) >> 16);  // RNE
}

__device__ __forceinline__ void async_ld16(const void* g, void* l) {
  __builtin_amdgcn_global_load_lds(
      (const __attribute__((address_space(1))) uint32_t*)g,
      (__attribute__((address_space(3))) uint32_t*)(uint32_t)(uintptr_t)l,
      16, 0, 0);
}

// ---------------- prep: rotate+transpose W -> Wt[N][K] bf16 ----------------
__global__ __launch_bounds__(256) void prep_w(const float* __restrict__ W,
                                              const float* __restrict__ theta,
                                              unsigned short* __restrict__ Wt) {
  __shared__ float csc[32], css[32];
  __shared__ unsigned short tile[64][72];  // [n_local][k_local], padded
  const int bk = blockIdx.x % 48, bn = blockIdx.x / 48;
  const int k0 = bk * 64, n0 = bn * 64;
  const int t = threadIdx.x;
  if (t < 32) {
    int d = n0 / 2 + t;
    float ang = theta[d] + theta[512 + d];
    csc[t] = cosf(ang); css[t] = sinf(ang);
  }
  __syncthreads();
#pragma unroll
  for (int i = 0; i < 8; ++i) {
    int idx = i * 256 + t;           // 2048 pairs = 64 k-rows x 32 pairs
    int pr = idx >> 5;               // k row 0..63
    int pc = idx & 31;               // pair col 0..31
    const float2 w2 = *(const float2*)&W[(size_t)(k0 + pr) * DM + n0 + pc * 2];
    float c = csc[pc], s = css[pc];
    tile[pc * 2][pr]     = f2bf(w2.x * c - w2.y * s);
    tile[pc * 2 + 1][pr] = f2bf(w2.x * s + w2.y * c);
  }
  __syncthreads();
#pragma unroll
  for (int i = 0; i < 16; ++i) {
    int idx = i * 256 + t;           // 4096 elems
    int r = idx >> 6, cdx = idx & 63;
    Wt[(size_t)(n0 + r) * KD + k0 + cdx] = tile[r][cdx];
  }
}

// ---------------- prep: rotated bias + zero page ----------------
__global__ void prep_bias(const float* __restrict__ b, const float* __restrict__ theta,
                          float* __restrict__ biasp, float* __restrict__ zp) {
  const int t = threadIdx.x;  // 512
  float ang = theta[t] + theta[512 + t];
  float c = cosf(ang), s = sinf(ang);
  float be = b[2 * t], bo = b[2 * t + 1];
  biasp[2 * t]     = be * c - bo * s;
  biasp[2 * t + 1] = be * s + bo * c;
  if (t < 256) ((float4*)zp)[t] = make_float4(0.f, 0.f, 0.f, 0.f);
}

// ---------------- prep: x -> bf16, seq-padded ----------------
__global__ __launch_bounds__(256) void prep_x(const float* __restrict__ x,
                                              unsigned short* __restrict__ xbp) {
  const size_t total = (size_t)NB * 8194 * 128;  // 16B chunks (8 bf16)
  for (size_t i = (size_t)blockIdx.x * 256 + threadIdx.x; i < total;
       i += (size_t)gridDim.x * 256) {
    int d8 = (int)(i & 127);
    size_t rem = i >> 7;
    int sp = (int)(rem % 8194);
    size_t bb = rem / 8194;
    uint4 o = make_uint4(0u, 0u, 0u, 0u);
    if (sp > 0 && sp < 8193) {
      const float4* src = (const float4*)(x + (bb * SEQ + (size_t)(sp - 1)) * DM + d8 * 8);
      float4 lo = src[0], hi = src[1];
      o.x = (uint32_t)f2bf(lo.x) | ((uint32_t)f2bf(lo.y) << 16);
      o.y = (uint32_t)f2bf(lo.z) | ((uint32_t)f2bf(lo.w) << 16);
      o.z = (uint32_t)f2bf(hi.x) | ((uint32_t)f2bf(hi.y) << 16);
      o.w = (uint32_t)f2bf(hi.z) | ((uint32_t)f2bf(hi.w) << 16);
    }
    ((uint4*)xbp)[i] = o;
  }
}

// ---- GEMM: 256x256, BK=32, 16 waves x (64x64), 4-ring, TLP-overlap --------
__global__ __launch_bounds__(1024, 4) void gemm256(const unsigned short* __restrict__ xbp,
                                                   const unsigned short* __restrict__ Wt,
                                                   const float* __restrict__ biasp,
                                                   float* __restrict__ out) {
  __shared__ __align__(16) unsigned char As[4][16384];  // [buf][256 rows][32 bf16]
  __shared__ __align__(16) unsigned char Bs[4][16384];  // [buf][256 nrow][32 bf16]

  const int tid = threadIdx.x;
  const int lane = tid & 63;
  const int wid = tid >> 6;                   // 0..15
  const int wm = wid >> 2, wn = wid & 3;      // 4M x 4N wave grid
  const int row16 = lane & 15, kgrp = lane >> 4;

  // XCD-bijective swizzle: 512 blocks = 8 XCD x (16 mtiles x 4 ntiles)
  const int L = blockIdx.x;
  const int xcd = L & 7;
  const int j = L >> 3;
  const int mtile = xcd * 16 + (j >> 2);
  const int ntile = j & 3;

  const int n0 = ntile * 256;
  const int batch = mtile >> 5;
  const int s0 = (mtile & 31) * 256;
  const size_t m0 = (size_t)mtile * 256;

  // fragment LDS byte offsets within a 16 KiB buffer (thread-constant)
  int aoff[4], boff[4];
#pragma unroll
  for (int mi = 0; mi < 4; ++mi) {
    int r = wm * 64 + mi * 16 + row16;
    aoff[mi] = r * 64 + (kgrp ^ ((r >> 1) & 3)) * 16;
  }
#pragma unroll
  for (int ni = 0; ni < 4; ++ni) {
    int r = wn * 64 + ni * 16 + row16;
    boff[ni] = r * 64 + (kgrp ^ ((r >> 1) & 3)) * 16;
  }

  // staging: 1024 threads, 1 load each per matrix per K-tile.
  // LDS dest LINEAR; global source chunk pre-swizzled (same XOR as reads).
  const int srow = tid >> 2, sc16 = tid & 3;
  const int scs = sc16 ^ ((srow >> 1) & 3);
  auto stageA = [&](int kt, int buf) {
    const int c = kt >> 5;
    const int ksb = (kt & 31) * 32;
    const size_t base = ((size_t)batch * 8194 + (size_t)(s0 + c)) * DM + ksb;
    async_ld16(xbp + base + (size_t)srow * DM + scs * 8, &As[buf][tid * 16]);
  };
  auto stageB = [&](int kt, int buf) {
    const int kb = kt * 32;
    async_ld16(Wt + (size_t)(n0 + srow) * KD + kb + scs * 8, &Bs[buf][tid * 16]);
  };

  f32x4 acc[4][4];
#pragma unroll
  for (int a = 0; a < 4; ++a)
#pragma unroll
    for (int b = 0; b < 4; ++b) acc[a][b] = (f32x4){0.f, 0.f, 0.f, 0.f};

  // prologue: stage kt 0,1,2 (2 loads each); confirm stage(0); barrier
  stageA(0, 0); stageB(0, 0);
  stageA(1, 1); stageB(1, 1);
  stageA(2, 2); stageB(2, 2);
  asm volatile("s_waitcnt vmcnt(4)" ::: "memory");
  __builtin_amdgcn_s_barrier();

  // per K-tile: stage kt+3, read own 8 frags, lgkm(0) (TLP hides the drain),
  // 16 MFMA under setprio, counted vmcnt, barrier.
  auto body = [&](int kt, int buf, int doStage, int vmN) {
    const int sbuf = (buf + 3) & 3;
    if (doStage) { stageA(kt + 3, sbuf); stageB(kt + 3, sbuf); }
    short8_t af[4], bf[4];
#pragma unroll
    for (int mi = 0; mi < 4; ++mi)
      af[mi] = *(const short8_t*)(&As[buf][0] + aoff[mi]);
#pragma unroll
    for (int ni = 0; ni < 4; ++ni)
      bf[ni] = *(const short8_t*)(&Bs[buf][0] + boff[ni]);
    asm volatile("s_waitcnt lgkmcnt(0)" ::: "memory");
    __builtin_amdgcn_sched_barrier(0);
    __builtin_amdgcn_s_setprio(1);
#pragma unroll
    for (int mi = 0; mi < 4; ++mi)
#pragma unroll
      for (int ni = 0; ni < 4; ++ni)
        acc[mi][ni] = __builtin_amdgcn_mfma_f32_16x16x32_bf16(
            af[mi], bf[ni], acc[mi][ni], 0, 0, 0);
    __builtin_amdgcn_s_setprio(0);
    if (vmN == 4)      asm volatile("s_waitcnt vmcnt(4)" ::: "memory");
    else if (vmN == 2) asm volatile("s_waitcnt vmcnt(2)" ::: "memory");
    else               asm volatile("s_waitcnt vmcnt(0)" ::: "memory");
    __builtin_amdgcn_sched_barrier(0);
    __builtin_amdgcn_s_barrier();
  };

  for (int kt4 = 0; kt4 < 92; kt4 += 4) {
    body(kt4 + 0, 0, 1, 4);
    body(kt4 + 1, 1, 1, 4);
    body(kt4 + 2, 2, 1, 4);
    body(kt4 + 3, 3, 1, 4);
  }
  // tail: kt92 stages kt95; then counted drains per the FIFO ledger
  body(92, 0, 1, 4);
  body(93, 1, 0, 2);
  body(94, 2, 0, 0);
  body(95, 3, 0, 0);

  // epilogue: C[row=kgrp*4+r, col=row16] per 16x16 fragment
#pragma unroll
  for (int mi = 0; mi < 4; ++mi) {
    size_t grow = m0 + (size_t)(wm * 64 + mi * 16 + kgrp * 4);
#pragma unroll
    for (int ni = 0; ni < 4; ++ni) {
      int col = n0 + wn * 64 + ni * 16 + row16;
      float bia = biasp[col];
      float* op = out + grow * DM + col;
#pragma unroll
      for (int r = 0; r < 4; ++r) op[(size_t)r * DM] = acc[mi][ni][r] + bia;
    }
  }
}

// ---------------- fallback GEMM (fp32 A direct), 128x128 2-barrier ----------
__global__ __launch_bounds__(256) void gemm_fb(const float* __restrict__ Ag,
                                               const unsigned short* __restrict__ Wt,
                                               const float* __restrict__ biasp,
                                               const float* __restrict__ zp,
                                               float* __restrict__ out) {
  __shared__ __align__(16) unsigned char As[128 * 64 * 4];
  __shared__ __align__(16) unsigned char Bs[128 * 64 * 2];

  const int tid = threadIdx.x;
  const int lane = tid & 63;
  const int wid = tid >> 6;
  const int wm = wid >> 1, wn = wid & 1;
  const int row16 = lane & 15, kgrp = lane >> 4;

  const int L = blockIdx.x;
  const int xcd = L & 7;
  const int j = L >> 3;
  const int mtile = xcd * 32 + (j >> 3);
  const int ntile = j & 7;

  const int n0 = ntile * 128;
  const int batch = mtile >> 6;
  const int s0 = (mtile & 63) * 128;
  const size_t m0 = (size_t)mtile * 128;

  f32x4 acc[4][4];
#pragma unroll
  for (int a = 0; a < 4; ++a)
#pragma unroll
    for (int b = 0; b < 4; ++b) acc[a][b] = (f32x4){0.f, 0.f, 0.f, 0.f};

  for (int kt = 0; kt < 48; ++kt) {
    const int c = kt >> 4;
    const int ksb = (kt & 15) * 64;
    __syncthreads();
#pragma unroll
    for (int it = 0; it < 8; ++it) {
      int f16 = it * 256 + tid;
      int row = f16 >> 4, c16 = f16 & 15;
      int c16s = c16 ^ (row & 7);
      int s = s0 + row + c - 1;
      const float* src = (s >= 0 && s < SEQ)
          ? Ag + ((size_t)batch * SEQ + (size_t)s) * DM + ksb + c16s * 4
          : zp + c16s * 4;
      async_ld16(src, As + f16 * 16);
    }
#pragma unroll
    for (int it = 0; it < 4; ++it) {
      int f16 = it * 256 + tid;
      int row = f16 >> 3, c16 = f16 & 7;
      int c16s = c16 ^ (row & 7);
      const unsigned short* src = Wt + (size_t)(n0 + row) * KD + kt * 64 + c16s * 8;
      async_ld16(src, Bs + f16 * 16);
    }
    __syncthreads();

#pragma unroll
    for (int kk = 0; kk < 2; ++kk) {
      short8_t af[4], bfr[4];
#pragma unroll
      for (int mi = 0; mi < 4; ++mi) {
        int r = wm * 64 + mi * 16 + row16;
        int kb = kk * 128 + kgrp * 32;
        f32x4 lo = *(const f32x4*)(As + r * 256 + (kb ^ ((r & 7) << 4)));
        f32x4 hi = *(const f32x4*)(As + r * 256 + ((kb + 16) ^ ((r & 7) << 4)));
        union { short8_t v; unsigned short u[8]; } pk;
        pk.u[0] = f2bf(lo[0]); pk.u[1] = f2bf(lo[1]);
        pk.u[2] = f2bf(lo[2]); pk.u[3] = f2bf(lo[3]);
        pk.u[4] = f2bf(hi[0]); pk.u[5] = f2bf(hi[1]);
        pk.u[6] = f2bf(hi[2]); pk.u[7] = f2bf(hi[3]);
        af[mi] = pk.v;
      }
#pragma unroll
      for (int ni = 0; ni < 4; ++ni) {
        int r = wn * 64 + ni * 16 + row16;
        int kb = kk * 64 + kgrp * 16;
        bfr[ni] = *(const short8_t*)(Bs + r * 128 + (kb ^ ((r & 7) << 4)));
      }
#pragma unroll
      for (int mi = 0; mi < 4; ++mi)
#pragma unroll
        for (int ni = 0; ni < 4; ++ni)
          acc[mi][ni] = __builtin_amdgcn_mfma_f32_16x16x32_bf16(
              af[mi], bfr[ni], acc[mi][ni], 0, 0, 0);
    }
  }

#pragma unroll
  for (int mi = 0; mi < 4; ++mi) {
    size_t grow = m0 + (size_t)(wm * 64 + mi * 16 + kgrp * 4);
#pragma unroll
    for (int ni = 0; ni < 4; ++ni) {
      int col = n0 + wn * 64 + ni * 16 + row16;
      float bia = biasp[col];
      float* op = out + grow * DM + col;
#pragma unroll
      for (int r = 0; r < 4; ++r) op[(size_t)r * DM] = acc[mi][ni][r] + bia;
    }
  }
}

// ---------------- pass 2: grouped (d%7) RMS norm, in-place ----------------
__global__ __launch_bounds__(256) void norm_kernel(float* __restrict__ y,
                                                   const float* __restrict__ gamma) {
  const int tid = threadIdx.x, lane = tid & 63, wv = tid >> 6;
  const size_t row = (size_t)blockIdx.x * 4 + wv;   // one wave per row
  float4* rp = (float4*)(y + row * DM);
  const float4* gp = (const float4*)gamma;
  float4 v[4];
#pragma unroll
  for (int jj = 0; jj < 4; ++jj) v[jj] = rp[jj * 64 + lane];

  float ss[7] = {0.f, 0.f, 0.f, 0.f, 0.f, 0.f, 0.f};
#pragma unroll
  for (int jj = 0; jj < 4; ++jj) {
    const float vv[4] = {v[jj].x, v[jj].y, v[jj].z, v[jj].w};
#pragma unroll
    for (int i = 0; i < 4; ++i) {
      int d = (jj * 64 + lane) * 4 + i;
      int g = d % 7;
      float sq = vv[i] * vv[i];
#pragma unroll
      for (int t = 0; t < 7; ++t) ss[t] += (g == t) ? sq : 0.f;
    }
  }
#pragma unroll
  for (int t = 0; t < 7; ++t) {
#pragma unroll
    for (int off = 32; off >= 1; off >>= 1) ss[t] += __shfl_xor(ss[t], off, 64);
  }
  float inv[7];
#pragma unroll
  for (int t = 0; t < 7; ++t) {
    float cnt = (t < 2) ? 147.f : 146.f;   // D=1024: groups 0,1 have 147 dims
    inv[t] = rsqrtf(ss[t] / cnt + 1e-6f);
  }
#pragma unroll
  for (int jj = 0; jj < 4; ++jj) {
    float4 g4 = gp[jj * 64 + lane];
    const float vv[4] = {v[jj].x, v[jj].y, v[jj].z, v[jj].w};
    const float gg[4] = {g4.x, g4.y, g4.z, g4.w};
    float o[4];
#pragma unroll
    for (int i = 0; i < 4; ++i) {
      int d = (jj * 64 + lane) * 4 + i;
      int g = d % 7;
      float iv = inv[0];
#pragma unroll
      for (int t = 1; t < 7; ++t) iv = (g == t) ? inv[t] : iv;
      o[i] = vv[i] * iv * gg[i];
    }
    rp[jj * 64 + lane] = make_float4(o[0], o[1], o[2], o[3]);
  }
}

extern "C" void kernel_launch(void* const* d_in, const int* in_sizes, int n_in,
                              void* d_out, int out_size, void* d_ws, size_t ws_size,
                              hipStream_t stream) {
  const float* x     = (const float*)d_in[0];
  const float* W     = (const float*)d_in[1];
  const float* b     = (const float*)d_in[2];
  const float* theta = (const float*)d_in[3];
  const float* gamma = (const float*)d_in[4];
  float* out = (float*)d_out;
  (void)in_sizes; (void)n_in; (void)out_size;

  char* ws = (char*)d_ws;
  unsigned short* Wt = (unsigned short*)ws;                 // 6,291,456 B
  float* biasp = (float*)(ws + 6291456);                    // 4 KiB
  float* zp    = (float*)(ws + 6291456 + 4096);             // 4 KiB zeros
  unsigned short* xbp = (unsigned short*)(ws + 6299648);    // 67,158,016 B
  const size_t needA = 6299648 + (size_t)NB * 8194 * DM * 2;

  prep_w<<<dim3(768), dim3(256), 0, stream>>>(W, theta, Wt);
  prep_bias<<<dim3(1), dim3(512), 0, stream>>>(b, theta, biasp, zp);

  if (ws_size >= needA) {
    prep_x<<<dim3(4096), dim3(256), 0, stream>>>(x, xbp);
    gemm256<<<dim3(512), dim3(1024), 0, stream>>>(xbp, Wt, biasp, out);
  } else {
    gemm_fb<<<dim3(2048), dim3(256), 0, stream>>>(x, Wt, biasp, zp, out);
  }
  norm_kernel<<<dim3(8192), dim3(256), 0, stream>>>(out, gamma);
}